// Round 2
// baseline (478.367 us; speedup 1.0000x reference)
//
#include <hip/hip_runtime.h>
#include <hip/hip_bf16.h>

#define HWN   4096
#define CIN   256
#define NINTER 128
#define NBATCH 4
#define BN_EPS 1e-5f

typedef __bf16 bf16_t;
typedef __bf16 bf16x8 __attribute__((ext_vector_type(8)));
typedef __bf16 bf16x4 __attribute__((ext_vector_type(4)));
typedef float  f32x4  __attribute__((ext_vector_type(4)));
typedef float  f32x16 __attribute__((ext_vector_type(16)));

// Workspace layout (bytes). hi/lo bf16 split everywhere that feeds softmax
// or the final BN-normalized conv. Total ~46.7 MiB.
#define OFF_QH  0
#define OFF_QL  4194304
#define OFF_KH  8388608
#define OFF_KL  12582912
#define OFF_V   16777216
#define OFF_YH  20971520
#define OFF_YL  25165824
#define OFF_WY  29360128
#define OFF_WBF 46137344   // 131072 bf16 hi, then 131072 bf16 lo (512 KiB)
#define OFF_ST  46661632

__device__ __forceinline__ void split_bf16(float v, bf16_t& h, bf16_t& l) {
  h = (bf16_t)v;
  l = (bf16_t)(v - (float)h);
}

__global__ __launch_bounds__(256) void convert_weights(
    const float* __restrict__ tw, const float* __restrict__ pw,
    const float* __restrict__ gw, const float* __restrict__ ww,
    bf16_t* __restrict__ out) {
  int i = blockIdx.x * 256 + threadIdx.x;  // 131072 total
  float v;
  if (i < 32768)        v = tw[i];
  else if (i < 65536)   v = pw[i - 32768];
  else if (i < 98304)   v = gw[i - 65536];
  else                  v = ww[i - 98304];
  bf16_t h, l;
  split_bf16(v, h, l);
  out[i] = h;
  out[131072 + i] = l;
}

// out[och][n] = sum_c w[och][c] x[c][n] + bias[och]; 32x32x16 bf16 MFMA,
// hi/lo split on both weight and x: acc = Wh*xh + Wh*xl + Wl*xh.
// wsel: 0->Q (n,d) hi/lo, 1->K (n,d) hi/lo, 2->V (d,m) single.
__global__ __launch_bounds__(256) void qkv_kernel(
    const float* __restrict__ x, const bf16_t* __restrict__ wbf,
    const float* __restrict__ tb, const float* __restrict__ pb,
    const float* __restrict__ gb,
    bf16_t* __restrict__ Qh, bf16_t* __restrict__ Ql,
    bf16_t* __restrict__ Kh, bf16_t* __restrict__ Kl,
    bf16_t* __restrict__ V) {
  const int ntb  = blockIdx.x;
  const int wsel = blockIdx.y;
  const int b    = blockIdx.z;
  const int tid  = threadIdx.x;
  const int lane = tid & 63;
  const int wv   = tid >> 6;
  const int l31  = lane & 31;
  const int half = lane >> 5;

  __shared__ __align__(16) bf16_t xTh[64][72];
  __shared__ __align__(16) bf16_t xTl[64][72];

  const bf16_t* wregh = wbf + wsel * 32768;            // [128][256] hi
  const bf16_t* wregl = wbf + 131072 + wsel * 32768;   // [128][256] lo
  const float*  xb    = x + (size_t)b * CIN * HWN + ntb * 64;

  f32x16 acc[2];
#pragma unroll
  for (int t = 0; t < 2; t++)
#pragma unroll
    for (int i = 0; i < 16; i++) acc[t][i] = 0.f;

  for (int c0 = 0; c0 < 256; c0 += 64) {
    __syncthreads();
#pragma unroll
    for (int i = 0; i < 16; i++) {
      int idx = tid + i * 256;
      int cc = idx >> 6;
      int nn = idx & 63;
      float v = xb[(size_t)(c0 + cc) * HWN + nn];
      bf16_t h, l;
      split_bf16(v, h, l);
      xTh[nn][cc] = h;
      xTl[nn][cc] = l;
    }
    __syncthreads();
#pragma unroll
    for (int kk = 0; kk < 64; kk += 16) {
      bf16x8 afh = *(const bf16x8*)(wregh + (size_t)(32 * wv + l31) * 256 + c0 + kk + half * 8);
      bf16x8 afl = *(const bf16x8*)(wregl + (size_t)(32 * wv + l31) * 256 + c0 + kk + half * 8);
      bf16x8 bh0 = *(const bf16x8*)(&xTh[l31][kk + half * 8]);
      bf16x8 bh1 = *(const bf16x8*)(&xTh[32 + l31][kk + half * 8]);
      bf16x8 bl0 = *(const bf16x8*)(&xTl[l31][kk + half * 8]);
      bf16x8 bl1 = *(const bf16x8*)(&xTl[32 + l31][kk + half * 8]);
      acc[0] = __builtin_amdgcn_mfma_f32_32x32x16_bf16(afh, bh0, acc[0], 0, 0, 0);
      acc[1] = __builtin_amdgcn_mfma_f32_32x32x16_bf16(afh, bh1, acc[1], 0, 0, 0);
      acc[0] = __builtin_amdgcn_mfma_f32_32x32x16_bf16(afh, bl0, acc[0], 0, 0, 0);
      acc[1] = __builtin_amdgcn_mfma_f32_32x32x16_bf16(afh, bl1, acc[1], 0, 0, 0);
      acc[0] = __builtin_amdgcn_mfma_f32_32x32x16_bf16(afl, bh0, acc[0], 0, 0, 0);
      acc[1] = __builtin_amdgcn_mfma_f32_32x32x16_bf16(afl, bh1, acc[1], 0, 0, 0);
    }
  }

  const float* bias = (wsel == 0) ? tb : (wsel == 1) ? pb : gb;
  if (wsel < 2) {
    bf16_t* dsth = (wsel == 0 ? Qh : Kh) + (size_t)b * HWN * NINTER;
    bf16_t* dstl = (wsel == 0 ? Ql : Kl) + (size_t)b * HWN * NINTER;
#pragma unroll
    for (int nt = 0; nt < 2; nt++) {
      int n = ntb * 64 + nt * 32 + l31;
#pragma unroll
      for (int rg = 0; rg < 4; rg++) {
        int och0 = 32 * wv + 8 * rg + 4 * half;
        bf16x4 v4h, v4l;
#pragma unroll
        for (int j = 0; j < 4; j++) {
          float v = acc[nt][rg * 4 + j] + bias[och0 + j];
          bf16_t h, l;
          split_bf16(v, h, l);
          v4h[j] = h;
          v4l[j] = l;
        }
        *(bf16x4*)(dsth + (size_t)n * NINTER + och0) = v4h;
        *(bf16x4*)(dstl + (size_t)n * NINTER + och0) = v4l;
      }
    }
  } else {
    bf16_t* dst = V + (size_t)b * NINTER * HWN;
#pragma unroll
    for (int nt = 0; nt < 2; nt++) {
      int m = ntb * 64 + nt * 32 + l31;
#pragma unroll
      for (int r = 0; r < 16; r++) {
        int och = 32 * wv + (r & 3) + 8 * (r >> 2) + 4 * half;
        dst[(size_t)och * HWN + m] = (bf16_t)(acc[nt][r] + bias[och]);
      }
    }
  }
}

// Flash attention, 64 q-rows/block, K-tile=64. S in hi/lo split precision:
// S = Qh Kh^T + Qh Kl^T + Ql Kh^T.
__global__ __launch_bounds__(256) void attn_kernel(
    const bf16_t* __restrict__ Qh, const bf16_t* __restrict__ Ql,
    const bf16_t* __restrict__ Kh, const bf16_t* __restrict__ Kl,
    const bf16_t* __restrict__ V,
    bf16_t* __restrict__ Yh, bf16_t* __restrict__ Yl) {
  const int qt   = blockIdx.x;
  const int b    = blockIdx.y;
  const int tid  = threadIdx.x;
  const int lane = tid & 63;
  const int wv   = tid >> 6;
  const int l15  = lane & 15;
  const int quad = lane >> 4;

  __shared__ __align__(16) bf16_t Kldsh[64][136];
  __shared__ __align__(16) bf16_t Kldsl[64][136];
  __shared__ __align__(16) bf16_t Vlds[128][72];
  __shared__ __align__(16) bf16_t Plds[4][16][72];

  const bf16_t* Qhb = Qh + (size_t)b * HWN * NINTER;
  const bf16_t* Qlb = Ql + (size_t)b * HWN * NINTER;
  const bf16_t* Khb = Kh + (size_t)b * HWN * NINTER;
  const bf16_t* Klb = Kl + (size_t)b * HWN * NINTER;
  const bf16_t* Vb  = V + (size_t)b * NINTER * HWN;

  bf16x8 qfh[4], qfl[4];
  const int qrow = qt * 64 + wv * 16 + l15;
#pragma unroll
  for (int kc = 0; kc < 4; kc++) {
    qfh[kc] = *(const bf16x8*)(Qhb + (size_t)qrow * NINTER + kc * 32 + quad * 8);
    qfl[kc] = *(const bf16x8*)(Qlb + (size_t)qrow * NINTER + kc * 32 + quad * 8);
  }

  f32x4 o[8];
#pragma unroll
  for (int dt = 0; dt < 8; dt++)
#pragma unroll
    for (int i = 0; i < 4; i++) o[dt][i] = 0.f;
  float m_run[4], l_run[4];
#pragma unroll
  for (int r = 0; r < 4; r++) { m_run[r] = -1e30f; l_run[r] = 0.f; }

  for (int kt = 0; kt < 64; kt++) {
    __syncthreads();
#pragma unroll
    for (int i = 0; i < 4; i++) {
      int idx = tid + i * 256;
      int row = idx >> 4;
      int c8 = (idx & 15) * 8;
      *(uint4*)(&Kldsh[row][c8]) =
          *(const uint4*)(Khb + (size_t)(kt * 64 + row) * NINTER + c8);
      *(uint4*)(&Kldsl[row][c8]) =
          *(const uint4*)(Klb + (size_t)(kt * 64 + row) * NINTER + c8);
    }
#pragma unroll
    for (int i = 0; i < 4; i++) {
      int idx = tid + i * 256;
      int row = idx >> 3;
      int c8 = (idx & 7) * 8;
      *(uint4*)(&Vlds[row][c8]) =
          *(const uint4*)(Vb + (size_t)row * HWN + kt * 64 + c8);
    }
    __syncthreads();

    f32x4 s[4];
#pragma unroll
    for (int nt = 0; nt < 4; nt++) {
#pragma unroll
      for (int i = 0; i < 4; i++) s[nt][i] = 0.f;
#pragma unroll
      for (int kc = 0; kc < 4; kc++) {
        bf16x8 kfh = *(const bf16x8*)(&Kldsh[nt * 16 + l15][kc * 32 + quad * 8]);
        bf16x8 kfl = *(const bf16x8*)(&Kldsl[nt * 16 + l15][kc * 32 + quad * 8]);
        s[nt] = __builtin_amdgcn_mfma_f32_16x16x32_bf16(qfh[kc], kfh, s[nt], 0, 0, 0);
        s[nt] = __builtin_amdgcn_mfma_f32_16x16x32_bf16(qfh[kc], kfl, s[nt], 0, 0, 0);
        s[nt] = __builtin_amdgcn_mfma_f32_16x16x32_bf16(qfl[kc], kfh, s[nt], 0, 0, 0);
      }
    }

#pragma unroll
    for (int r = 0; r < 4; r++) {
      float vmax = fmaxf(fmaxf(s[0][r], s[1][r]), fmaxf(s[2][r], s[3][r]));
#pragma unroll
      for (int off = 1; off < 16; off <<= 1)
        vmax = fmaxf(vmax, __shfl_xor(vmax, off));
      float m_new = fmaxf(m_run[r], vmax);
      float alpha = __expf(m_run[r] - m_new);
      m_run[r] = m_new;
      float rsum = 0.f;
#pragma unroll
      for (int nt = 0; nt < 4; nt++) {
        float p = __expf(s[nt][r] - m_new);
        s[nt][r] = p;
        rsum += p;
      }
#pragma unroll
      for (int off = 1; off < 16; off <<= 1)
        rsum += __shfl_xor(rsum, off);
      l_run[r] = l_run[r] * alpha + rsum;
#pragma unroll
      for (int dt = 0; dt < 8; dt++) o[dt][r] *= alpha;
    }

#pragma unroll
    for (int nt = 0; nt < 4; nt++)
#pragma unroll
      for (int r = 0; r < 4; r++)
        Plds[wv][quad * 4 + r][nt * 16 + l15] = (bf16_t)s[nt][r];

#pragma unroll
    for (int kc = 0; kc < 2; kc++) {
      bf16x8 pf = *(const bf16x8*)(&Plds[wv][l15][kc * 32 + quad * 8]);
#pragma unroll
      for (int dt = 0; dt < 8; dt++) {
        bf16x8 vf = *(const bf16x8*)(&Vlds[dt * 16 + l15][kc * 32 + quad * 8]);
        o[dt] = __builtin_amdgcn_mfma_f32_16x16x32_bf16(pf, vf, o[dt], 0, 0, 0);
      }
    }
  }

  bf16_t* Yhb = Yh + (size_t)b * HWN * NINTER;
  bf16_t* Ylb = Yl + (size_t)b * HWN * NINTER;
#pragma unroll
  for (int r = 0; r < 4; r++) {
    float inv = 1.f / l_run[r];
    int n = qt * 64 + wv * 16 + quad * 4 + r;
#pragma unroll
    for (int dt = 0; dt < 8; dt++) {
      float v = o[dt][r] * inv;
      bf16_t h, l;
      split_bf16(v, h, l);
      Yhb[(size_t)n * NINTER + dt * 16 + l15] = h;
      Ylb[(size_t)n * NINTER + dt * 16 + l15] = l;
    }
  }
}

// wy[co][n] = sum_i W[co][i] Y[n][i] + Wb[co], hi/lo split on both operands.
__global__ __launch_bounds__(256) void wconv_kernel(
    const bf16_t* __restrict__ Wbf,
    const bf16_t* __restrict__ Yhp, const bf16_t* __restrict__ Ylp,
    const float* __restrict__ Wb, float* __restrict__ WY) {
  const int ntb = blockIdx.x;
  const int b   = blockIdx.y;
  const int tid = threadIdx.x;
  const int lane = tid & 63;
  const int wv   = tid >> 6;
  const int l31  = lane & 31;
  const int half = lane >> 5;

  const bf16_t* Wh = Wbf + 98304;            // [256][128] hi
  const bf16_t* Wl = Wbf + 131072 + 98304;   // [256][128] lo
  const bf16_t* Yh = Yhp + (size_t)b * HWN * NINTER + (size_t)ntb * 64 * NINTER;
  const bf16_t* Yl = Ylp + (size_t)b * HWN * NINTER + (size_t)ntb * 64 * NINTER;

  f32x16 acc[2][2];
#pragma unroll
  for (int a = 0; a < 2; a++)
#pragma unroll
    for (int c = 0; c < 2; c++)
#pragma unroll
      for (int i = 0; i < 16; i++) acc[a][c][i] = 0.f;

#pragma unroll
  for (int k0 = 0; k0 < 128; k0 += 16) {
    bf16x8 a0h = *(const bf16x8*)(Wh + (size_t)(wv * 64 + l31) * NINTER + k0 + half * 8);
    bf16x8 a1h = *(const bf16x8*)(Wh + (size_t)(wv * 64 + 32 + l31) * NINTER + k0 + half * 8);
    bf16x8 a0l = *(const bf16x8*)(Wl + (size_t)(wv * 64 + l31) * NINTER + k0 + half * 8);
    bf16x8 a1l = *(const bf16x8*)(Wl + (size_t)(wv * 64 + 32 + l31) * NINTER + k0 + half * 8);
    bf16x8 b0h = *(const bf16x8*)(Yh + (size_t)l31 * NINTER + k0 + half * 8);
    bf16x8 b1h = *(const bf16x8*)(Yh + (size_t)(32 + l31) * NINTER + k0 + half * 8);
    bf16x8 b0l = *(const bf16x8*)(Yl + (size_t)l31 * NINTER + k0 + half * 8);
    bf16x8 b1l = *(const bf16x8*)(Yl + (size_t)(32 + l31) * NINTER + k0 + half * 8);
    acc[0][0] = __builtin_amdgcn_mfma_f32_32x32x16_bf16(a0h, b0h, acc[0][0], 0, 0, 0);
    acc[0][1] = __builtin_amdgcn_mfma_f32_32x32x16_bf16(a0h, b1h, acc[0][1], 0, 0, 0);
    acc[1][0] = __builtin_amdgcn_mfma_f32_32x32x16_bf16(a1h, b0h, acc[1][0], 0, 0, 0);
    acc[1][1] = __builtin_amdgcn_mfma_f32_32x32x16_bf16(a1h, b1h, acc[1][1], 0, 0, 0);
    acc[0][0] = __builtin_amdgcn_mfma_f32_32x32x16_bf16(a0h, b0l, acc[0][0], 0, 0, 0);
    acc[0][1] = __builtin_amdgcn_mfma_f32_32x32x16_bf16(a0h, b1l, acc[0][1], 0, 0, 0);
    acc[1][0] = __builtin_amdgcn_mfma_f32_32x32x16_bf16(a1h, b0l, acc[1][0], 0, 0, 0);
    acc[1][1] = __builtin_amdgcn_mfma_f32_32x32x16_bf16(a1h, b1l, acc[1][1], 0, 0, 0);
    acc[0][0] = __builtin_amdgcn_mfma_f32_32x32x16_bf16(a0l, b0h, acc[0][0], 0, 0, 0);
    acc[0][1] = __builtin_amdgcn_mfma_f32_32x32x16_bf16(a0l, b1h, acc[0][1], 0, 0, 0);
    acc[1][0] = __builtin_amdgcn_mfma_f32_32x32x16_bf16(a1l, b0h, acc[1][0], 0, 0, 0);
    acc[1][1] = __builtin_amdgcn_mfma_f32_32x32x16_bf16(a1l, b1h, acc[1][1], 0, 0, 0);
  }

  float* dst = WY + (size_t)b * 256 * HWN + ntb * 64;
#pragma unroll
  for (int ct = 0; ct < 2; ct++)
#pragma unroll
    for (int nt = 0; nt < 2; nt++)
#pragma unroll
      for (int r = 0; r < 16; r++) {
        int co = wv * 64 + ct * 32 + (r & 3) + 8 * (r >> 2) + 4 * half;
        int n = nt * 32 + l31;
        dst[(size_t)co * HWN + n] = acc[ct][nt][r] + Wb[co];
      }
}

__global__ __launch_bounds__(256) void stats_kernel(
    const float* __restrict__ WY, float* __restrict__ stats) {
  const int c = blockIdx.x;
  const int tid = threadIdx.x;
  float s = 0.f, s2 = 0.f;
  for (int b = 0; b < NBATCH; b++) {
    const float* p = WY + ((size_t)b * 256 + c) * HWN;
    for (int i = tid; i < HWN; i += 256) {
      float v = p[i];
      s += v;
      s2 += v * v;
    }
  }
#pragma unroll
  for (int off = 1; off < 64; off <<= 1) {
    s += __shfl_xor(s, off);
    s2 += __shfl_xor(s2, off);
  }
  __shared__ float red[8];
  int wv = tid >> 6;
  if ((tid & 63) == 0) { red[wv] = s; red[4 + wv] = s2; }
  __syncthreads();
  if (tid == 0) {
    float S = red[0] + red[1] + red[2] + red[3];
    float S2 = red[4] + red[5] + red[6] + red[7];
    float mean = S * (1.f / 16384.f);
    float var = S2 * (1.f / 16384.f) - mean * mean;
    stats[c] = mean;
    stats[256 + c] = rsqrtf(var + BN_EPS);
  }
}

__global__ __launch_bounds__(256) void bn_kernel(
    const float* __restrict__ WY, const float* __restrict__ x,
    const float* __restrict__ stats, const float* __restrict__ gamma,
    const float* __restrict__ beta, float* __restrict__ out) {
  int idx = blockIdx.x * 256 + threadIdx.x;  // 1048576 float4 groups
  int e = idx * 4;
  int c = (e >> 12) & 255;
  float4 wy = *(const float4*)(WY + e);
  float4 xv = *(const float4*)(x + e);
  float mean = stats[c];
  float g = gamma[c] * stats[256 + c];
  float bb = beta[c];
  float4 o;
  o.x = g * (wy.x - mean) + bb + xv.x;
  o.y = g * (wy.y - mean) + bb + xv.y;
  o.z = g * (wy.z - mean) + bb + xv.z;
  o.w = g * (wy.w - mean) + bb + xv.w;
  *(float4*)(out + e) = o;
}

extern "C" void kernel_launch(void* const* d_in, const int* in_sizes, int n_in,
                              void* d_out, int out_size, void* d_ws, size_t ws_size,
                              hipStream_t stream) {
  const float* x       = (const float*)d_in[0];
  const float* theta_b = (const float*)d_in[2];
  const float* phi_b   = (const float*)d_in[4];
  const float* g_b     = (const float*)d_in[6];
  const float* W_b     = (const float*)d_in[8];
  const float* bn_g    = (const float*)d_in[9];
  const float* bn_b    = (const float*)d_in[10];
  float* out = (float*)d_out;

  char* ws = (char*)d_ws;
  bf16_t* Qh  = (bf16_t*)(ws + OFF_QH);
  bf16_t* Ql  = (bf16_t*)(ws + OFF_QL);
  bf16_t* Kh  = (bf16_t*)(ws + OFF_KH);
  bf16_t* Kl  = (bf16_t*)(ws + OFF_KL);
  bf16_t* V   = (bf16_t*)(ws + OFF_V);
  bf16_t* Yh  = (bf16_t*)(ws + OFF_YH);
  bf16_t* Yl  = (bf16_t*)(ws + OFF_YL);
  float*  WY  = (float*)(ws + OFF_WY);
  bf16_t* WBF = (bf16_t*)(ws + OFF_WBF);
  float*  ST  = (float*)(ws + OFF_ST);

  convert_weights<<<512, 256, 0, stream>>>(
      (const float*)d_in[1], (const float*)d_in[3],
      (const float*)d_in[5], (const float*)d_in[7], WBF);
  qkv_kernel<<<dim3(64, 3, NBATCH), 256, 0, stream>>>(
      x, WBF, theta_b, phi_b, g_b, Qh, Ql, Kh, Kl, V);
  attn_kernel<<<dim3(64, NBATCH), 256, 0, stream>>>(Qh, Ql, Kh, Kl, V, Yh, Yl);
  wconv_kernel<<<dim3(64, NBATCH), 256, 0, stream>>>(WBF, Yh, Yl, W_b, WY);
  stats_kernel<<<256, 256, 0, stream>>>(WY, ST);
  bn_kernel<<<4096, 256, 0, stream>>>(WY, x, ST, bn_g, bn_b, out);
}

// Round 4
// 300.207 us; speedup vs baseline: 1.5935x; 1.5935x over previous
//
#include <hip/hip_runtime.h>
#include <hip/hip_bf16.h>

#define HWN   4096
#define CIN   256
#define NINTER 128
#define NBATCH 4
#define BN_EPS 1e-5f
#define NC    4          // key chunks for attention pass 1
#define CHUNK 1024       // keys per chunk
#define LOG2E 1.4426950408889634f

typedef __bf16 bf16_t;
typedef __bf16 bf16x8 __attribute__((ext_vector_type(8)));
typedef __bf16 bf16x4 __attribute__((ext_vector_type(4)));
typedef float  f32x4  __attribute__((ext_vector_type(4)));
typedef float  f32x16 __attribute__((ext_vector_type(16)));

// fast 2^x on the VALU transcendental pipe (avoids glibc __exp2f collision)
__device__ __forceinline__ float fexp2(float x) {
  return __builtin_amdgcn_exp2f(x);
}

// Workspace layout (bytes). Opart (32 MB) overlaps WY (16 MB): Opart is dead
// before wconv writes WY (stream-ordered). Total ~64 MB.
#define OFF_QH  0
#define OFF_QL  4194304
#define OFF_KH  8388608
#define OFF_KL  12582912
#define OFF_V   16777216
#define OFF_YH  20971520
#define OFF_YL  25165824
#define OFF_WY  29360128   // 16 MiB (fp32)
#define OFF_OP  29360128   // 32 MiB (fp32)  -- overlaps WY, dead before wconv
#define OFF_MP  62914560   // 256 KiB
#define OFF_LP  63176704   // 256 KiB
#define OFF_WBF 63438848   // 512 KiB (hi then lo)
#define OFF_ST  63963136   // 2 KiB

__device__ __forceinline__ void split_bf16(float v, bf16_t& h, bf16_t& l) {
  h = (bf16_t)v;
  l = (bf16_t)(v - (float)h);
}

__global__ __launch_bounds__(256) void convert_weights(
    const float* __restrict__ tw, const float* __restrict__ pw,
    const float* __restrict__ gw, const float* __restrict__ ww,
    bf16_t* __restrict__ out) {
  int i = blockIdx.x * 256 + threadIdx.x;  // 131072 total
  float v;
  if (i < 32768)        v = tw[i];
  else if (i < 65536)   v = pw[i - 32768];
  else if (i < 98304)   v = gw[i - 65536];
  else                  v = ww[i - 98304];
  bf16_t h, l;
  split_bf16(v, h, l);
  out[i] = h;
  out[131072 + i] = l;
}

// out[och][n] = sum_c w[och][c] x[c][n] + bias; n-tile 32, grid (128,3,4).
// wsel: 0->Q (n,d) hi/lo, scaled by log2(e); 1->K (n,d) hi/lo; 2->V (d,m).
__global__ __launch_bounds__(256, 4) void qkv_kernel(
    const float* __restrict__ x, const bf16_t* __restrict__ wbf,
    const float* __restrict__ tb, const float* __restrict__ pb,
    const float* __restrict__ gb,
    bf16_t* __restrict__ Qh, bf16_t* __restrict__ Ql,
    bf16_t* __restrict__ Kh, bf16_t* __restrict__ Kl,
    bf16_t* __restrict__ V) {
  const int ntb  = blockIdx.x;   // 128 tiles of 32 n
  const int wsel = blockIdx.y;
  const int b    = blockIdx.z;
  const int tid  = threadIdx.x;
  const int lane = tid & 63;
  const int wv   = tid >> 6;
  const int l31  = lane & 31;
  const int half = lane >> 5;

  __shared__ __align__(16) bf16_t xTh[32][72];
  __shared__ __align__(16) bf16_t xTl[32][72];

  const bf16_t* wregh = wbf + wsel * 32768;            // [128][256] hi
  const bf16_t* wregl = wbf + 131072 + wsel * 32768;   // [128][256] lo
  const float*  xb    = x + (size_t)b * CIN * HWN + ntb * 32;

  f32x16 acc;
#pragma unroll
  for (int i = 0; i < 16; i++) acc[i] = 0.f;

  for (int c0 = 0; c0 < 256; c0 += 64) {
    __syncthreads();
#pragma unroll
    for (int i = 0; i < 8; i++) {         // 2048 elements: 64c x 32n
      int idx = tid + i * 256;
      int cc = idx >> 5;
      int nn = idx & 31;
      float v = xb[(size_t)(c0 + cc) * HWN + nn];
      bf16_t h, l;
      split_bf16(v, h, l);
      xTh[nn][cc] = h;
      xTl[nn][cc] = l;
    }
    __syncthreads();
#pragma unroll
    for (int kk = 0; kk < 64; kk += 16) {
      bf16x8 afh = *(const bf16x8*)(wregh + (size_t)(32 * wv + l31) * 256 + c0 + kk + half * 8);
      bf16x8 afl = *(const bf16x8*)(wregl + (size_t)(32 * wv + l31) * 256 + c0 + kk + half * 8);
      bf16x8 bh0 = *(const bf16x8*)(&xTh[l31][kk + half * 8]);
      bf16x8 bl0 = *(const bf16x8*)(&xTl[l31][kk + half * 8]);
      acc = __builtin_amdgcn_mfma_f32_32x32x16_bf16(afh, bh0, acc, 0, 0, 0);
      acc = __builtin_amdgcn_mfma_f32_32x32x16_bf16(afh, bl0, acc, 0, 0, 0);
      acc = __builtin_amdgcn_mfma_f32_32x32x16_bf16(afl, bh0, acc, 0, 0, 0);
    }
  }

  const float* bias = (wsel == 0) ? tb : (wsel == 1) ? pb : gb;
  if (wsel < 2) {
    bf16_t* dsth = (wsel == 0 ? Qh : Kh) + (size_t)b * HWN * NINTER;
    bf16_t* dstl = (wsel == 0 ? Ql : Kl) + (size_t)b * HWN * NINTER;
    const float scale = (wsel == 0) ? LOG2E : 1.0f;
    int n = ntb * 32 + l31;
#pragma unroll
    for (int rg = 0; rg < 4; rg++) {
      int och0 = 32 * wv + 8 * rg + 4 * half;
      bf16x4 v4h, v4l;
#pragma unroll
      for (int j = 0; j < 4; j++) {
        float v = (acc[rg * 4 + j] + bias[och0 + j]) * scale;
        bf16_t h, l;
        split_bf16(v, h, l);
        v4h[j] = h;
        v4l[j] = l;
      }
      *(bf16x4*)(dsth + (size_t)n * NINTER + och0) = v4h;
      *(bf16x4*)(dstl + (size_t)n * NINTER + och0) = v4l;
    }
  } else {
    bf16_t* dst = V + (size_t)b * NINTER * HWN;
    int m = ntb * 32 + l31;
#pragma unroll
    for (int r = 0; r < 16; r++) {
      int och = 32 * wv + (r & 3) + 8 * (r >> 2) + 4 * half;
      dst[(size_t)och * HWN + m] = (bf16_t)(acc[r] + bias[och]);
    }
  }
}

// Flash attention pass 1: grid (64 qt, NC chunk, 4 b), 4 waves x 16 q rows.
// Keys [chunk*1024, +1024) in 32 tiles of 32. Base-2 softmax (Q pre-scaled).
// Writes unnormalized O partial + (m, l) per chunk.
__global__ __launch_bounds__(256, 4) void attn_kernel(
    const bf16_t* __restrict__ Qh, const bf16_t* __restrict__ Ql,
    const bf16_t* __restrict__ Kh, const bf16_t* __restrict__ Kl,
    const bf16_t* __restrict__ V,
    float* __restrict__ Opart, float* __restrict__ Mp, float* __restrict__ Lp) {
  const int qt    = blockIdx.x;
  const int chunk = blockIdx.y;
  const int b     = blockIdx.z;
  const int tid   = threadIdx.x;
  const int lane  = tid & 63;
  const int wv    = tid >> 6;
  const int l15   = lane & 15;
  const int quad  = lane >> 4;
  const int kbase = chunk * CHUNK;

  __shared__ __align__(16) bf16_t Kldsh[32][136];
  __shared__ __align__(16) bf16_t Kldsl[32][136];
  __shared__ __align__(16) bf16_t Vlds[128][56];
  __shared__ __align__(16) bf16_t Plds[4][16][40];

  const bf16_t* Qhb = Qh + (size_t)b * HWN * NINTER;
  const bf16_t* Qlb = Ql + (size_t)b * HWN * NINTER;
  const bf16_t* Khb = Kh + (size_t)b * HWN * NINTER;
  const bf16_t* Klb = Kl + (size_t)b * HWN * NINTER;
  const bf16_t* Vb  = V + (size_t)b * NINTER * HWN;

  bf16x8 qfh[4], qfl[4];
  const int qrow = qt * 64 + wv * 16 + l15;
#pragma unroll
  for (int kc = 0; kc < 4; kc++) {
    qfh[kc] = *(const bf16x8*)(Qhb + (size_t)qrow * NINTER + kc * 32 + quad * 8);
    qfl[kc] = *(const bf16x8*)(Qlb + (size_t)qrow * NINTER + kc * 32 + quad * 8);
  }

  f32x4 o[8];
#pragma unroll
  for (int dt = 0; dt < 8; dt++)
#pragma unroll
    for (int i = 0; i < 4; i++) o[dt][i] = 0.f;
  float m_run[4], l_run[4];
#pragma unroll
  for (int r = 0; r < 4; r++) { m_run[r] = -1e30f; l_run[r] = 0.f; }

  for (int t = 0; t < 32; t++) {
    __syncthreads();
#pragma unroll
    for (int i = 0; i < 2; i++) {          // K tile: 32 rows x 128 d
      int idx = tid + i * 256;
      int row = idx >> 4;
      int c8 = (idx & 15) * 8;
      *(uint4*)(&Kldsh[row][c8]) =
          *(const uint4*)(Khb + (size_t)(kbase + t * 32 + row) * NINTER + c8);
      *(uint4*)(&Kldsl[row][c8]) =
          *(const uint4*)(Klb + (size_t)(kbase + t * 32 + row) * NINTER + c8);
    }
#pragma unroll
    for (int i = 0; i < 2; i++) {          // V tile: 128 d x 32 m
      int idx = tid + i * 256;
      int row = idx >> 2;
      int c8 = (idx & 3) * 8;
      *(uint4*)(&Vlds[row][c8]) =
          *(const uint4*)(Vb + (size_t)row * HWN + kbase + t * 32 + c8);
    }
    __syncthreads();

    f32x4 s[2];
#pragma unroll
    for (int nt = 0; nt < 2; nt++) {
#pragma unroll
      for (int i = 0; i < 4; i++) s[nt][i] = 0.f;
#pragma unroll
      for (int kc = 0; kc < 4; kc++) {
        bf16x8 kfh = *(const bf16x8*)(&Kldsh[nt * 16 + l15][kc * 32 + quad * 8]);
        bf16x8 kfl = *(const bf16x8*)(&Kldsl[nt * 16 + l15][kc * 32 + quad * 8]);
        s[nt] = __builtin_amdgcn_mfma_f32_16x16x32_bf16(qfh[kc], kfh, s[nt], 0, 0, 0);
        s[nt] = __builtin_amdgcn_mfma_f32_16x16x32_bf16(qfh[kc], kfl, s[nt], 0, 0, 0);
        s[nt] = __builtin_amdgcn_mfma_f32_16x16x32_bf16(qfl[kc], kfh, s[nt], 0, 0, 0);
      }
    }

#pragma unroll
    for (int r = 0; r < 4; r++) {
      float vmax = fmaxf(s[0][r], s[1][r]);
#pragma unroll
      for (int off = 1; off < 16; off <<= 1)
        vmax = fmaxf(vmax, __shfl_xor(vmax, off));
      float m_new = fmaxf(m_run[r], vmax);
      float alpha = fexp2(m_run[r] - m_new);
      m_run[r] = m_new;
      float p0 = fexp2(s[0][r] - m_new);
      float p1 = fexp2(s[1][r] - m_new);
      s[0][r] = p0;
      s[1][r] = p1;
      float rsum = p0 + p1;
#pragma unroll
      for (int off = 1; off < 16; off <<= 1)
        rsum += __shfl_xor(rsum, off);
      l_run[r] = l_run[r] * alpha + rsum;
#pragma unroll
      for (int dt = 0; dt < 8; dt++) o[dt][r] *= alpha;
    }

#pragma unroll
    for (int nt = 0; nt < 2; nt++)
#pragma unroll
      for (int r = 0; r < 4; r++)
        Plds[wv][quad * 4 + r][nt * 16 + l15] = (bf16_t)s[nt][r];

    bf16x8 pf = *(const bf16x8*)(&Plds[wv][l15][quad * 8]);
#pragma unroll
    for (int dt = 0; dt < 8; dt++) {
      bf16x8 vf = *(const bf16x8*)(&Vlds[dt * 16 + l15][quad * 8]);
      o[dt] = __builtin_amdgcn_mfma_f32_16x16x32_bf16(pf, vf, o[dt], 0, 0, 0);
    }
  }

  float* Ob = Opart + ((size_t)(b * NC + chunk) * HWN) * NINTER;
#pragma unroll
  for (int r = 0; r < 4; r++) {
    int n = qt * 64 + wv * 16 + quad * 4 + r;
#pragma unroll
    for (int dt = 0; dt < 8; dt++)
      Ob[(size_t)n * NINTER + dt * 16 + l15] = o[dt][r];
    if (l15 == 0) {
      Mp[(size_t)(b * NC + chunk) * HWN + n] = m_run[r];
      Lp[(size_t)(b * NC + chunk) * HWN + n] = l_run[r];
    }
  }
}

// Combine NC chunk partials -> Y (bf16 hi/lo). One thread per (b,n,d4).
__global__ __launch_bounds__(256, 4) void attn_combine(
    const float* __restrict__ Opart, const float* __restrict__ Mp,
    const float* __restrict__ Lp,
    bf16_t* __restrict__ Yh, bf16_t* __restrict__ Yl) {
  int gid = blockIdx.x * 256 + threadIdx.x;   // 524288 total
  int d4 = gid & 31;
  int n = (gid >> 5) & 4095;
  int b = gid >> 17;

  float mi[NC];
  float m = -1e30f;
#pragma unroll
  for (int c = 0; c < NC; c++) {
    mi[c] = Mp[(size_t)(b * NC + c) * HWN + n];
    m = fmaxf(m, mi[c]);
  }
  float lsum = 0.f;
  float4 acc = make_float4(0.f, 0.f, 0.f, 0.f);
  const float4* Op4 = (const float4*)Opart;
#pragma unroll
  for (int c = 0; c < NC; c++) {
    float w = fexp2(mi[c] - m);
    lsum += w * Lp[(size_t)(b * NC + c) * HWN + n];
    float4 ov = Op4[((size_t)(b * NC + c) * HWN + n) * 32 + d4];
    acc.x += w * ov.x;
    acc.y += w * ov.y;
    acc.z += w * ov.z;
    acc.w += w * ov.w;
  }
  float inv = 1.f / lsum;
  bf16x4 yh, yl;
  float vals[4] = {acc.x * inv, acc.y * inv, acc.z * inv, acc.w * inv};
#pragma unroll
  for (int j = 0; j < 4; j++) {
    bf16_t h, l;
    split_bf16(vals[j], h, l);
    yh[j] = h;
    yl[j] = l;
  }
  size_t base = ((size_t)b * HWN + n) * NINTER + d4 * 4;
  *(bf16x4*)(Yh + base) = yh;
  *(bf16x4*)(Yl + base) = yl;
}

// wy[co][n] = sum_i W[co][i] Y[n][i] + Wb[co]; n-tile 32, grid (128,4).
__global__ __launch_bounds__(256, 4) void wconv_kernel(
    const bf16_t* __restrict__ Wbf,
    const bf16_t* __restrict__ Yhp, const bf16_t* __restrict__ Ylp,
    const float* __restrict__ Wb, float* __restrict__ WY) {
  const int ntb = blockIdx.x;
  const int b   = blockIdx.y;
  const int tid = threadIdx.x;
  const int lane = tid & 63;
  const int wv   = tid >> 6;
  const int l31  = lane & 31;
  const int half = lane >> 5;

  const bf16_t* Wh = Wbf + 98304;            // [256][128] hi
  const bf16_t* Wl = Wbf + 131072 + 98304;   // [256][128] lo
  const bf16_t* Yhr = Yhp + (size_t)b * HWN * NINTER + (size_t)ntb * 32 * NINTER;
  const bf16_t* Ylr = Ylp + (size_t)b * HWN * NINTER + (size_t)ntb * 32 * NINTER;

  f32x16 acc[2];
#pragma unroll
  for (int c = 0; c < 2; c++)
#pragma unroll
    for (int i = 0; i < 16; i++) acc[c][i] = 0.f;

#pragma unroll
  for (int k0 = 0; k0 < 128; k0 += 16) {
    bf16x8 a0h = *(const bf16x8*)(Wh + (size_t)(wv * 64 + l31) * NINTER + k0 + half * 8);
    bf16x8 a1h = *(const bf16x8*)(Wh + (size_t)(wv * 64 + 32 + l31) * NINTER + k0 + half * 8);
    bf16x8 a0l = *(const bf16x8*)(Wl + (size_t)(wv * 64 + l31) * NINTER + k0 + half * 8);
    bf16x8 a1l = *(const bf16x8*)(Wl + (size_t)(wv * 64 + 32 + l31) * NINTER + k0 + half * 8);
    bf16x8 b0h = *(const bf16x8*)(Yhr + (size_t)l31 * NINTER + k0 + half * 8);
    bf16x8 b0l = *(const bf16x8*)(Ylr + (size_t)l31 * NINTER + k0 + half * 8);
    acc[0] = __builtin_amdgcn_mfma_f32_32x32x16_bf16(a0h, b0h, acc[0], 0, 0, 0);
    acc[0] = __builtin_amdgcn_mfma_f32_32x32x16_bf16(a0h, b0l, acc[0], 0, 0, 0);
    acc[0] = __builtin_amdgcn_mfma_f32_32x32x16_bf16(a0l, b0h, acc[0], 0, 0, 0);
    acc[1] = __builtin_amdgcn_mfma_f32_32x32x16_bf16(a1h, b0h, acc[1], 0, 0, 0);
    acc[1] = __builtin_amdgcn_mfma_f32_32x32x16_bf16(a1h, b0l, acc[1], 0, 0, 0);
    acc[1] = __builtin_amdgcn_mfma_f32_32x32x16_bf16(a1l, b0h, acc[1], 0, 0, 0);
  }

  float* dst = WY + (size_t)b * 256 * HWN + ntb * 32;
#pragma unroll
  for (int ct = 0; ct < 2; ct++)
#pragma unroll
    for (int r = 0; r < 16; r++) {
      int co = wv * 64 + ct * 32 + (r & 3) + 8 * (r >> 2) + 4 * half;
      dst[(size_t)co * HWN + l31] = acc[ct][r] + Wb[co];
    }
}

__global__ __launch_bounds__(256) void stats_kernel(
    const float* __restrict__ WY, float* __restrict__ stats) {
  const int c = blockIdx.x;
  const int tid = threadIdx.x;
  float s = 0.f, s2 = 0.f;
  for (int b = 0; b < NBATCH; b++) {
    const float* p = WY + ((size_t)b * 256 + c) * HWN;
    for (int i = tid; i < HWN; i += 256) {
      float v = p[i];
      s += v;
      s2 += v * v;
    }
  }
#pragma unroll
  for (int off = 1; off < 64; off <<= 1) {
    s += __shfl_xor(s, off);
    s2 += __shfl_xor(s2, off);
  }
  __shared__ float red[8];
  int wv = tid >> 6;
  if ((tid & 63) == 0) { red[wv] = s; red[4 + wv] = s2; }
  __syncthreads();
  if (tid == 0) {
    float S = red[0] + red[1] + red[2] + red[3];
    float S2 = red[4] + red[5] + red[6] + red[7];
    float mean = S * (1.f / 16384.f);
    float var = S2 * (1.f / 16384.f) - mean * mean;
    stats[c] = mean;
    stats[256 + c] = rsqrtf(var + BN_EPS);
  }
}

__global__ __launch_bounds__(256) void bn_kernel(
    const float* __restrict__ WY, const float* __restrict__ x,
    const float* __restrict__ stats, const float* __restrict__ gamma,
    const float* __restrict__ beta, float* __restrict__ out) {
  int idx = blockIdx.x * 256 + threadIdx.x;
  int e = idx * 4;
  int c = (e >> 12) & 255;
  float4 wy = *(const float4*)(WY + e);
  float4 xv = *(const float4*)(x + e);
  float mean = stats[c];
  float g = gamma[c] * stats[256 + c];
  float bb = beta[c];
  float4 o;
  o.x = g * (wy.x - mean) + bb + xv.x;
  o.y = g * (wy.y - mean) + bb + xv.y;
  o.z = g * (wy.z - mean) + bb + xv.z;
  o.w = g * (wy.w - mean) + bb + xv.w;
  *(float4*)(out + e) = o;
}

extern "C" void kernel_launch(void* const* d_in, const int* in_sizes, int n_in,
                              void* d_out, int out_size, void* d_ws, size_t ws_size,
                              hipStream_t stream) {
  const float* x       = (const float*)d_in[0];
  const float* theta_b = (const float*)d_in[2];
  const float* phi_b   = (const float*)d_in[4];
  const float* g_b     = (const float*)d_in[6];
  const float* W_b     = (const float*)d_in[8];
  const float* bn_g    = (const float*)d_in[9];
  const float* bn_b    = (const float*)d_in[10];
  float* out = (float*)d_out;

  char* ws = (char*)d_ws;
  bf16_t* Qh  = (bf16_t*)(ws + OFF_QH);
  bf16_t* Ql  = (bf16_t*)(ws + OFF_QL);
  bf16_t* Kh  = (bf16_t*)(ws + OFF_KH);
  bf16_t* Kl  = (bf16_t*)(ws + OFF_KL);
  bf16_t* V   = (bf16_t*)(ws + OFF_V);
  bf16_t* Yh  = (bf16_t*)(ws + OFF_YH);
  bf16_t* Yl  = (bf16_t*)(ws + OFF_YL);
  float*  WY  = (float*)(ws + OFF_WY);
  float*  OP  = (float*)(ws + OFF_OP);
  float*  MP  = (float*)(ws + OFF_MP);
  float*  LP  = (float*)(ws + OFF_LP);
  bf16_t* WBF = (bf16_t*)(ws + OFF_WBF);
  float*  ST  = (float*)(ws + OFF_ST);

  convert_weights<<<512, 256, 0, stream>>>(
      (const float*)d_in[1], (const float*)d_in[3],
      (const float*)d_in[5], (const float*)d_in[7], WBF);
  qkv_kernel<<<dim3(128, 3, NBATCH), 256, 0, stream>>>(
      x, WBF, theta_b, phi_b, g_b, Qh, Ql, Kh, Kl, V);
  attn_kernel<<<dim3(64, NC, NBATCH), 256, 0, stream>>>(
      Qh, Ql, Kh, Kl, V, OP, MP, LP);
  attn_combine<<<2048, 256, 0, stream>>>(OP, MP, LP, Yh, Yl);
  wconv_kernel<<<dim3(128, NBATCH), 256, 0, stream>>>(WBF, Yh, Yl, W_b, WY);
  stats_kernel<<<256, 256, 0, stream>>>(WY, ST);
  bn_kernel<<<4096, 256, 0, stream>>>(WY, x, ST, bn_g, bn_b, out);
}